// Round 4
// baseline (784.532 us; speedup 1.0000x reference)
//
#include <hip/hip_runtime.h>
#include <stdint.h>

#define JAX_PARTITIONABLE 1

#define N_PTS    10000
#define BATCH    2048
#define MAX_ITER 10
#define NMODELS  (BATCH*MAX_ITER)

// ---------------- threefry2x32 (JAX-exact, 20 rounds) ----------------
// rotl via v_alignbit_b32: alignbit(v,v,s) = rotr(v,s); rotl(v,d) = rotr(v,32-d).
#define ROTL(v,d) __builtin_amdgcn_alignbit((v),(v),(uint32_t)(32-(d)))

// rounds only: assumes x0 += k0, x1 += k1 already applied by caller
__device__ __forceinline__ void threefry_rounds(uint32_t k0, uint32_t k1, uint32_t ks2,
                                                uint32_t &x0, uint32_t &x1){
#define TF_R(r) { x0 += x1; x1 = ROTL(x1,(r)); x1 ^= x0; }
  TF_R(13) TF_R(15) TF_R(26) TF_R(6)
  x0 += k1;  x1 += ks2 + 1u;
  TF_R(17) TF_R(29) TF_R(16) TF_R(24)
  x0 += ks2; x1 += k0 + 2u;
  TF_R(13) TF_R(15) TF_R(26) TF_R(6)
  x0 += k0;  x1 += k1 + 3u;
  TF_R(17) TF_R(29) TF_R(16) TF_R(24)
  x0 += k1;  x1 += ks2 + 4u;
  TF_R(13) TF_R(15) TF_R(26) TF_R(6)
  x0 += ks2; x1 += k0 + 5u;
#undef TF_R
}

__device__ __forceinline__ void threefry2x32(uint32_t k0, uint32_t k1, uint32_t &x0, uint32_t &x1){
  const uint32_t ks2 = k0 ^ k1 ^ 0x1BD11BDAu;
  x0 += k0; x1 += k1;
  threefry_rounds(k0, k1, ks2, x0, x1);
}

// ---------------- top-4 helpers (key = (mant23 << 32) | ~index) ----------------
__device__ __forceinline__ void top4_insert(unsigned long long a[4], unsigned long long key){
  if (key > a[3]){
    if (key > a[0]){ a[3]=a[2]; a[2]=a[1]; a[1]=a[0]; a[0]=key; }
    else if (key > a[1]){ a[3]=a[2]; a[2]=a[1]; a[1]=key; }
    else if (key > a[2]){ a[3]=a[2]; a[2]=key; }
    else { a[3]=key; }
  }
}

// merges per-thread sorted-desc 4-lists across a 256-thread block; result in a[] of tid 0
__device__ void block_merge_top4(unsigned long long a[4], unsigned long long* sm, int tid){
  sm[tid*4+0]=a[0]; sm[tid*4+1]=a[1]; sm[tid*4+2]=a[2]; sm[tid*4+3]=a[3];
  __syncthreads();
  for (int s = 128; s >= 1; s >>= 1){
    if (tid < s){
      unsigned long long bv[4];
      bv[0]=sm[(tid+s)*4+0]; bv[1]=sm[(tid+s)*4+1]; bv[2]=sm[(tid+s)*4+2]; bv[3]=sm[(tid+s)*4+3];
      unsigned long long ov[4];
      int pa=0, pb=0;
      #pragma unroll
      for (int k=0;k<4;k++){
        unsigned long long va = (pa<4)?a[pa]:0ull;
        unsigned long long vb = (pb<4)?bv[pb]:0ull;
        bool ta = va >= vb;
        ov[k] = ta ? va : vb;
        pa += ta?1:0; pb += ta?0:1;
      }
      a[0]=ov[0]; a[1]=ov[1]; a[2]=ov[2]; a[3]=ov[3];
      sm[tid*4+0]=a[0]; sm[tid*4+1]=a[1]; sm[tid*4+2]=a[2]; sm[tid*4+3]=a[3];
    }
    __syncthreads();
  }
}

__device__ __forceinline__ unsigned int lane_lt_count(unsigned long long m){
  unsigned int c = __builtin_amdgcn_mbcnt_lo((uint32_t)m, 0u);
  return __builtin_amdgcn_mbcnt_hi((uint32_t)(m >> 32), c);
}

// ---------------- sampling ----------------
#if JAX_PARTITIONABLE
// split (foldlike): key_t = (y0,y1) of threefry((0,42), 0, t)
// bits[j] = y0^y1 of threefry(key_t, 0, j), j = b*N_PTS + i ; uniform mant = bits>>9
// Threshold filter: P(bits >= TH_BITS) = 0.0064/pt => ~64 survivors/row (~16/wave).
// Ballot + mbcnt compaction into per-wave LDS regions: zero LDS atomics; a check with
// no survivors in the wave costs 1 v_cmp + scalar branch. Exact-rescan fallback
// guards count<4 / per-wave cap overflow => unconditionally exact.
#define TH_BITS 4267479552u   // (8388608 - 53687) << 9
#define WCAP 96               // per-wave candidate cap; survivors/wave ~ Poisson(16)

__global__ __launch_bounds__(256) void sample_topk(int* __restrict__ idxs){
  const int b = blockIdx.x;      // row 0..2047
  const int t = blockIdx.y;      // iteration 0..9
  const int tid = threadIdx.x;
  uint32_t k0 = 0u, k1 = (uint32_t)t;
  threefry2x32(0u, 42u, k0, k1);           // iteration key (both halves)
  const uint32_t ks2 = k0 ^ k1 ^ 0x1BD11BDAu;

  __shared__ unsigned long long wcand[4*WCAP];
  __shared__ unsigned long long sm[256*4];
  __shared__ unsigned int wcnts[4];

  const unsigned int wbase = (unsigned int)(tid >> 6) * WCAP;
  unsigned int wcnt = 0;                   // wave-uniform survivor count (SGPR)

  const uint32_t jb = (uint32_t)(b * N_PTS) + k1;   // x1 init = j + k1 (wrapping, as JAX)

#define EMIT(u, idx) { \
    unsigned long long mk = __ballot((u) >= TH_BITS); \
    if (mk){ \
      if ((u) >= TH_BITS){ \
        unsigned int slot = wcnt + lane_lt_count(mk); \
        if (slot < WCAP) \
          wcand[wbase + slot] = ((unsigned long long)((u) >> 9) << 32) | (uint32_t)(~(idx)); \
      } \
      wcnt += (unsigned int)__popcll(mk); \
    } }

  // 10 iterations x 4 chains x 256 threads = 10240 >= N_PTS; OOB masked on last iter
  uint32_t x1b = jb + (uint32_t)tid;
  for (int iter = 0; iter < 10; ++iter, x1b += 1024u){
    uint32_t a0=k0, a1=k0, a2=k0, a3=k0;
    uint32_t b0=x1b, b1=x1b+256u, b2=x1b+512u, b3=x1b+768u;
#define QR4(r) { a0+=b0; b0=ROTL(b0,r); b0^=a0;  a1+=b1; b1=ROTL(b1,r); b1^=a1; \
                 a2+=b2; b2=ROTL(b2,r); b2^=a2;  a3+=b3; b3=ROTL(b3,r); b3^=a3; }
#define INJ4(p,q) { a0+=(p); b0+=(q); a1+=(p); b1+=(q); a2+=(p); b2+=(q); a3+=(p); b3+=(q); }
    QR4(13) QR4(15) QR4(26) QR4(6)
    INJ4(k1,  ks2 + 1u)
    QR4(17) QR4(29) QR4(16) QR4(24)
    INJ4(ks2, k0 + 2u)
    QR4(13) QR4(15) QR4(26) QR4(6)
    INJ4(k0,  k1 + 3u)
    QR4(17) QR4(29) QR4(16) QR4(24)
    INJ4(k1,  ks2 + 4u)
    QR4(13) QR4(15) QR4(26) QR4(6)
    INJ4(ks2, k0 + 5u)
#undef QR4
#undef INJ4
    uint32_t u0 = a0^b0, u1 = a1^b1, u2 = a2^b2, u3 = a3^b3;
    const uint32_t ibase = (uint32_t)(iter*1024) + (uint32_t)tid;
    if (iter == 9){                        // mask points >= N_PTS (uniform branch)
      u0 = (ibase        < (uint32_t)N_PTS) ? u0 : 0u;
      u1 = (ibase + 256u < (uint32_t)N_PTS) ? u1 : 0u;
      u2 = (ibase + 512u < (uint32_t)N_PTS) ? u2 : 0u;
      u3 = (ibase + 768u < (uint32_t)N_PTS) ? u3 : 0u;
    }
    EMIT(u0, ibase)
    EMIT(u1, ibase + 256u)
    EMIT(u2, ibase + 512u)
    EMIT(u3, ibase + 768u)
  }
#undef EMIT

  if ((tid & 63) == 0) wcnts[tid >> 6] = wcnt;
  __syncthreads();
  const unsigned int c0 = wcnts[0], c1 = wcnts[1], c2 = wcnts[2], c3 = wcnts[3];
  const unsigned int n = c0 + c1 + c2 + c3;
  const bool good = (n >= 4u) && (c0 <= WCAP) && (c1 <= WCAP) && (c2 <= WCAP) && (c3 <= WCAP);

  unsigned long long a[4] = {0ull,0ull,0ull,0ull};
  if (good){
    #pragma unroll
    for (int w = 0; w < 4; ++w){
      const unsigned int cw = wcnts[w];
      for (unsigned int j = tid; j < cw; j += 256) top4_insert(a, wcand[w*WCAP + j]);
    }
  } else {
    // exact fallback (probability ~1e-20 per row; correctness guarantee)
    for (int i = tid; i < N_PTS; i += 256){
      uint32_t x0 = k0, x1 = jb + (uint32_t)i;
      threefry_rounds(k0, k1, ks2, x0, x1);
      uint32_t u = x0 ^ x1;
      unsigned long long key = ((unsigned long long)(u >> 9) << 32) | (uint32_t)(~(uint32_t)i);
      top4_insert(a, key);
    }
  }
  block_merge_top4(a, sm, tid);
  if (tid == 0){
    int base = ((t*BATCH)+b)*4;
    idxs[base+0] = (int)(~(uint32_t)(a[0] & 0xffffffffull));
    idxs[base+1] = (int)(~(uint32_t)(a[1] & 0xffffffffull));
    idxs[base+2] = (int)(~(uint32_t)(a[2] & 0xffffffffull));
    idxs[base+3] = (int)(~(uint32_t)(a[3] & 0xffffffffull));
  }
}
#else
__global__ __launch_bounds__(256) void sample_topk(int* __restrict__ idxs){
  const int b = blockIdx.x;
  const int t = blockIdx.y;
  const int tid = threadIdx.x;
  uint32_t k0, k1;
  {
    int i0 = 2*t, i1 = 2*t+1;
    uint32_t u0, u1;
    if (i0 < 10){ u0=(uint32_t)i0; u1=(uint32_t)(i0+10); threefry2x32(0u,42u,u0,u1); k0=u0; }
    else        { u0=(uint32_t)(i0-10); u1=(uint32_t)i0; threefry2x32(0u,42u,u0,u1); k0=u1; }
    if (i1 < 10){ u0=(uint32_t)i1; u1=(uint32_t)(i1+10); threefry2x32(0u,42u,u0,u1); k1=u0; }
    else        { u0=(uint32_t)(i1-10); u1=(uint32_t)i1; threefry2x32(0u,42u,u0,u1); k1=u1; }
  }
  const uint32_t half = 10240000u;
  unsigned long long aLo[4] = {0,0,0,0}, aHi[4] = {0,0,0,0};
  const uint32_t jbase = (uint32_t)(b * N_PTS);
  for (int i = tid; i < N_PTS; i += 256){
    uint32_t x0 = jbase + (uint32_t)i, x1 = x0 + half;
    threefry2x32(k0, k1, x0, x1);
    unsigned long long kLo = ((unsigned long long)(x0 >> 9) << 32) | (uint32_t)(~(uint32_t)i);
    unsigned long long kHi = ((unsigned long long)(x1 >> 9) << 32) | (uint32_t)(~(uint32_t)i);
    top4_insert(aLo, kLo);
    top4_insert(aHi, kHi);
  }
  __shared__ unsigned long long sm[256*4];
  block_merge_top4(aLo, sm, tid);
  if (tid == 0){
    int base = ((t*BATCH)+b)*4;
    for (int s=0;s<4;s++) idxs[base+s] = (int)(~(uint32_t)(aLo[s] & 0xffffffffull));
  }
  __syncthreads();
  block_merge_top4(aHi, sm, tid);
  if (tid == 0){
    int base = ((t*BATCH)+(b+1024))*4;
    for (int s=0;s<4;s++) idxs[base+s] = (int)(~(uint32_t)(aHi[s] & 0xffffffffull));
  }
}
#endif

// ---------------- DLT: 4-point normalized homography, double precision ----------------
__global__ __launch_bounds__(64) void dlt_kernel(const float* __restrict__ kp1,
                                                 const float* __restrict__ kp2,
                                                 const int* __restrict__ idxs,
                                                 float* __restrict__ Hout,
                                                 float* __restrict__ Hinvout,
                                                 int* __restrict__ validout){
  const int m = blockIdx.x*64 + threadIdx.x;   // grid exact: 320*64 == NMODELS
  __shared__ double As[64][73];
  double* A = &As[threadIdx.x][0];

  double p1x[4],p1y[4],p2x[4],p2y[4];
  #pragma unroll
  for (int s=0;s<4;s++){
    int id = idxs[m*4+s];
    float2 a = ((const float2*)kp1)[id];
    float2 b = ((const float2*)kp2)[id];
    p1x[s]=a.x; p1y[s]=a.y; p2x[s]=b.x; p2y[s]=b.y;
  }
  double mx1=0,my1=0,mx2=0,my2=0;
  #pragma unroll
  for (int s=0;s<4;s++){ mx1+=p1x[s]; my1+=p1y[s]; mx2+=p2x[s]; my2+=p2y[s]; }
  mx1*=0.25; my1*=0.25; mx2*=0.25; my2*=0.25;
  double d1=0,d2=0;
  #pragma unroll
  for (int s=0;s<4;s++){
    d1 += sqrt((p1x[s]-mx1)*(p1x[s]-mx1) + (p1y[s]-my1)*(p1y[s]-my1));
    d2 += sqrt((p2x[s]-mx2)*(p2x[s]-mx2) + (p2y[s]-my2)*(p2y[s]-my2));
  }
  d1*=0.25; d2*=0.25;
  const double s1 = sqrt(2.0)/(d1 + 1e-8);
  const double s2 = sqrt(2.0)/(d2 + 1e-8);
  #pragma unroll
  for (int s=0;s<4;s++){
    double X1=(p1x[s]-mx1)*s1, Y1=(p1y[s]-my1)*s1;
    double X2=(p2x[s]-mx2)*s2, Y2=(p2y[s]-my2)*s2;
    double* ra = A + s*9;
    ra[0]=0.0; ra[1]=0.0; ra[2]=0.0; ra[3]=-X1; ra[4]=-Y1; ra[5]=-1.0;
    ra[6]=Y2*X1; ra[7]=Y2*Y1; ra[8]=Y2;
    double* rb = A + (4+s)*9;
    rb[0]=X1; rb[1]=Y1; rb[2]=1.0; rb[3]=0.0; rb[4]=0.0; rb[5]=0.0;
    rb[6]=-X2*X1; rb[7]=-X2*Y1; rb[8]=-X2;
  }
  for (int k=0;k<8;k++){
    int piv=k; double pv=fabs(A[k*9+k]);
    for (int r=k+1;r<8;r++){ double v=fabs(A[r*9+k]); if (v>pv){pv=v;piv=r;} }
    if (piv!=k){
      for (int c=k;c<9;c++){ double tmp=A[k*9+c]; A[k*9+c]=A[piv*9+c]; A[piv*9+c]=tmp; }
    }
    double invp = 1.0/A[k*9+k];
    for (int r=k+1;r<8;r++){
      double f = A[r*9+k]*invp;
      for (int c=k+1;c<9;c++) A[r*9+c] -= f*A[k*9+c];
      A[r*9+k]=0.0;
    }
  }
  double h[9];
  h[8]=1.0;
  for (int k=7;k>=0;k--){
    double ssum=0.0;
    for (int c=k+1;c<9;c++) ssum += A[k*9+c]*h[c];
    h[k] = -ssum / A[k*9+k];
  }
  {
    double nn=0.0;
    #pragma unroll
    for (int i=0;i<9;i++) nn += h[i]*h[i];
    double inr = 1.0/sqrt(nn);
    #pragma unroll
    for (int i=0;i<9;i++) h[i]*=inr;
  }
  double M[9];
  #pragma unroll
  for (int r=0;r<3;r++){
    double h0=h[r*3+0], h1=h[r*3+1], h2=h[r*3+2];
    M[r*3+0] = h0*s1;
    M[r*3+1] = h1*s1;
    M[r*3+2] = h0*(-s1*mx1) + h1*(-s1*my1) + h2;
  }
  double Hd[9];
  const double is2 = 1.0/s2;
  #pragma unroll
  for (int c=0;c<3;c++){
    Hd[0*3+c] = M[0*3+c]*is2 + mx2*M[2*3+c];
    Hd[1*3+c] = M[1*3+c]*is2 + my2*M[2*3+c];
    Hd[2*3+c] = M[2*3+c];
  }
  const double dn = 1.0/(Hd[8] + 1e-8);
  #pragma unroll
  for (int i=0;i<9;i++) Hd[i]*=dn;
  float Hf[9];
  #pragma unroll
  for (int i=0;i<9;i++){ Hf[i]=(float)Hd[i]; Hout[m*9+i]=Hf[i]; }
  float mind = fminf(fminf(fabsf(Hf[0]),fabsf(Hf[4])),fabsf(Hf[8]));
  validout[m] = (mind > 1e-6f) ? 1 : 0;
  {
    double a=Hd[0],b=Hd[1],c=Hd[2],d=Hd[3],e=Hd[4],f=Hd[5],g=Hd[6],hh=Hd[7],ii=Hd[8];
    double C00= e*ii-f*hh, C01=-(d*ii-f*g), C02= d*hh-e*g;
    double det = a*C00 + b*C01 + c*C02;
    double idet = 1.0/det;
    double inv[9];
    inv[0]=C00*idet;        inv[1]=(c*hh-b*ii)*idet; inv[2]=(b*f-c*e)*idet;
    inv[3]=C01*idet;        inv[4]=(a*ii-c*g)*idet;  inv[5]=(c*d-a*f)*idet;
    inv[6]=C02*idet;        inv[7]=(b*g-a*hh)*idet;  inv[8]=(a*e-b*d)*idet;
    #pragma unroll
    for (int i=0;i<9;i++) Hinvout[m*9+i]=(float)inv[i];
  }
}

// ---------------- symmetric transfer error, f32, contraction-free ----------------
// e2 >= 0 (or NaN->false), so e1 > 2.0 already decides "not inlier" — bit-exact early exit.
__device__ __forceinline__ int inlier_test(float x1,float y1,float x2,float y2,
                                           const float* __restrict__ H,
                                           const float* __restrict__ Hi){
  float px = __fadd_rn(__fadd_rn(__fmul_rn(H[0],x1), __fmul_rn(H[1],y1)), H[2]);
  float py = __fadd_rn(__fadd_rn(__fmul_rn(H[3],x1), __fmul_rn(H[4],y1)), H[5]);
  float pz = __fadd_rn(__fadd_rn(__fmul_rn(H[6],x1), __fmul_rn(H[7],y1)), H[8]);
  float sc = (fabsf(pz) > 1e-8f) ? __fdiv_rn(1.0f, pz) : 1.0f;
  float dx = __fsub_rn(__fmul_rn(px,sc), x2);
  float dy = __fsub_rn(__fmul_rn(py,sc), y2);
  float e1 = __fadd_rn(__fmul_rn(dx,dx), __fmul_rn(dy,dy));
  if (!(e1 <= 2.0f)) return 0;          // covers e1 > 2 and e1 = NaN
  float qx = __fadd_rn(__fadd_rn(__fmul_rn(Hi[0],x2), __fmul_rn(Hi[1],y2)), Hi[2]);
  float qy = __fadd_rn(__fadd_rn(__fmul_rn(Hi[3],x2), __fmul_rn(Hi[4],y2)), Hi[5]);
  float qz = __fadd_rn(__fadd_rn(__fmul_rn(Hi[6],x2), __fmul_rn(Hi[7],y2)), Hi[8]);
  float sc2 = (fabsf(qz) > 1e-8f) ? __fdiv_rn(1.0f, qz) : 1.0f;
  float ex = __fsub_rn(__fmul_rn(qx,sc2), x1);
  float ey = __fsub_rn(__fmul_rn(qy,sc2), y1);
  float e2 = __fadd_rn(__fmul_rn(ex,ex), __fmul_rn(ey,ey));
  float err = __fadd_rn(e1, e2);
  return (err <= 2.0f) ? 1 : 0;   // NaN -> 0, matches jnp
}

// ---------------- scoring: 8 models per block ----------------
#define MODELS_PER_BLOCK 8
__global__ __launch_bounds__(256) void score_kernel(const float* __restrict__ kp1,
                                                    const float* __restrict__ kp2,
                                                    const float* __restrict__ Hall,
                                                    const float* __restrict__ Hinvall,
                                                    const int* __restrict__ validall,
                                                    float* __restrict__ scores){
  const int m0 = blockIdx.x * MODELS_PER_BLOCK;
  const int tid = threadIdx.x;
  __shared__ float sH[MODELS_PER_BLOCK][9], sHi[MODELS_PER_BLOCK][9];
  if (tid < 9*MODELS_PER_BLOCK)        sH [tid/9][tid%9] = Hall[m0*9 + tid];
  else if (tid < 18*MODELS_PER_BLOCK){ int q = tid - 9*MODELS_PER_BLOCK;
                                       sHi[q/9][q%9] = Hinvall[m0*9 + q]; }
  __syncthreads();
  int cnt[MODELS_PER_BLOCK];
  #pragma unroll
  for (int mm=0;mm<MODELS_PER_BLOCK;mm++) cnt[mm]=0;
  for (int i = tid; i < N_PTS; i += 256){
    float2 p1 = ((const float2*)kp1)[i];
    float2 p2 = ((const float2*)kp2)[i];
    #pragma unroll
    for (int mm=0;mm<MODELS_PER_BLOCK;mm++)
      cnt[mm] += inlier_test(p1.x,p1.y,p2.x,p2.y,sH[mm],sHi[mm]);
  }
  // wave-shuffle reduce, then cross-wave via LDS
  __shared__ int wred[4][MODELS_PER_BLOCK];
  const int lane = tid & 63, wid = tid >> 6;
  #pragma unroll
  for (int mm=0;mm<MODELS_PER_BLOCK;mm++){
    int v = cnt[mm];
    for (int off=32; off; off>>=1) v += __shfl_down(v, off, 64);
    if (lane==0) wred[wid][mm] = v;
  }
  __syncthreads();
  if (tid < MODELS_PER_BLOCK){
    int v = wred[0][tid]+wred[1][tid]+wred[2][tid]+wred[3][tid];
    scores[m0+tid] = validall[m0+tid] ? (float)v : -1.0f;
  }
}

// ---------------- selection: max score, ties -> earliest linear index ----------------
__global__ __launch_bounds__(1024) void select_kernel(const float* __restrict__ scores,
                                                      int* __restrict__ winner){
  __shared__ unsigned long long sm[1024];
  const int tid = threadIdx.x;
  unsigned long long best = 0ull;
  for (int i = tid; i < NMODELS; i += 1024){
    float s = scores[i];
    uint32_t hi = (uint32_t)(int)(s + 2.0f);   // -1 -> 1, count c -> c+2 (exact ints)
    unsigned long long key = ((unsigned long long)hi << 32) | (uint32_t)(~(uint32_t)i);
    if (key > best) best = key;
  }
  sm[tid]=best; __syncthreads();
  for (int s=512;s;s>>=1){ if (tid<s && sm[tid+s]>sm[tid]) sm[tid]=sm[tid+s]; __syncthreads(); }
  if (tid==0){
    unsigned long long k = sm[0];
    winner[0] = (int)(~(uint32_t)(k & 0xffffffffull));
    winner[1] = ((uint32_t)(k >> 32) >= 4u) ? 1 : 0;  // score>=2 beats init best_score=1.0
  }
}

// ---------------- finalize: write H + inlier mask ----------------
__global__ __launch_bounds__(256) void finalize_kernel(const float* __restrict__ kp1,
                                                       const float* __restrict__ kp2,
                                                       const float* __restrict__ Hall,
                                                       const float* __restrict__ Hinvall,
                                                       const int* __restrict__ winner,
                                                       float* __restrict__ out){
  __shared__ float sH[9], sHi[9];
  const int w = winner[0];
  const int ok = winner[1];
  if (threadIdx.x < 9){
    float idv = (threadIdx.x % 4 == 0) ? 1.0f : 0.0f;
    sH[threadIdx.x]  = ok ? Hall[w*9+threadIdx.x]    : idv;
    sHi[threadIdx.x] = ok ? Hinvall[w*9+threadIdx.x] : idv;
  }
  __syncthreads();
  if (blockIdx.x==0 && threadIdx.x<9) out[threadIdx.x] = sH[threadIdx.x];
  const int i = blockIdx.x*256 + threadIdx.x;
  if (i < N_PTS){
    float2 p1 = ((const float2*)kp1)[i];
    float2 p2 = ((const float2*)kp2)[i];
    int inl = ok ? inlier_test(p1.x,p1.y,p2.x,p2.y,sH,sHi) : 0;
    out[9+i] = inl ? 1.0f : 0.0f;
  }
}

// ---------------- launch ----------------
extern "C" void kernel_launch(void* const* d_in, const int* in_sizes, int n_in,
                              void* d_out, int out_size, void* d_ws, size_t ws_size,
                              hipStream_t stream) {
  (void)in_sizes; (void)n_in; (void)out_size; (void)ws_size;
  const float* kp1 = (const float*)d_in[0];
  const float* kp2 = (const float*)d_in[1];
  float* out = (float*)d_out;
  char* ws = (char*)d_ws;
  int*   idxs    = (int*)  (ws + 0);          // NMODELS*4 int  = 327,680 B
  float* Hall    = (float*)(ws + 327680);     // NMODELS*9 f32  = 737,280 B
  float* Hinvall = (float*)(ws + 1064960);    // NMODELS*9 f32  = 737,280 B
  int*   validall= (int*)  (ws + 1802240);    // NMODELS int    =  81,920 B
  float* scores  = (float*)(ws + 1884160);    // NMODELS f32    =  81,920 B
  int*   winner  = (int*)  (ws + 1966080);    // 2 ints

#if JAX_PARTITIONABLE
  sample_topk<<<dim3(BATCH, MAX_ITER), 256, 0, stream>>>(idxs);
#else
  sample_topk<<<dim3(BATCH/2, MAX_ITER), 256, 0, stream>>>(idxs);
#endif
  dlt_kernel<<<dim3(NMODELS/64), 64, 0, stream>>>(kp1, kp2, idxs, Hall, Hinvall, validall);
  score_kernel<<<dim3(NMODELS/MODELS_PER_BLOCK), 256, 0, stream>>>(kp1, kp2, Hall, Hinvall, validall, scores);
  select_kernel<<<1, 1024, 0, stream>>>(scores, winner);
  finalize_kernel<<<dim3((N_PTS+255)/256), 256, 0, stream>>>(kp1, kp2, Hall, Hinvall, winner, out);
}

// Round 5
// 727.566 us; speedup vs baseline: 1.0783x; 1.0783x over previous
//
#include <hip/hip_runtime.h>
#include <stdint.h>

#define JAX_PARTITIONABLE 1

#define N_PTS    10000
#define BATCH    2048
#define MAX_ITER 10
#define NMODELS  (BATCH*MAX_ITER)

// ---------------- threefry2x32 (JAX-exact, 20 rounds) ----------------
// rotl via v_alignbit_b32: alignbit(v,v,s) = rotr(v,s); rotl(v,d) = rotr(v,32-d).
#define ROTL(v,d) __builtin_amdgcn_alignbit((v),(v),(uint32_t)(32-(d)))

// rounds only: assumes x0 += k0, x1 += k1 already applied by caller
__device__ __forceinline__ void threefry_rounds(uint32_t k0, uint32_t k1, uint32_t ks2,
                                                uint32_t &x0, uint32_t &x1){
#define TF_R(r) { x0 += x1; x1 = ROTL(x1,(r)); x1 ^= x0; }
  TF_R(13) TF_R(15) TF_R(26) TF_R(6)
  x0 += k1;  x1 += ks2 + 1u;
  TF_R(17) TF_R(29) TF_R(16) TF_R(24)
  x0 += ks2; x1 += k0 + 2u;
  TF_R(13) TF_R(15) TF_R(26) TF_R(6)
  x0 += k0;  x1 += k1 + 3u;
  TF_R(17) TF_R(29) TF_R(16) TF_R(24)
  x0 += k1;  x1 += ks2 + 4u;
  TF_R(13) TF_R(15) TF_R(26) TF_R(6)
  x0 += ks2; x1 += k0 + 5u;
#undef TF_R
}

__device__ __forceinline__ void threefry2x32(uint32_t k0, uint32_t k1, uint32_t &x0, uint32_t &x1){
  const uint32_t ks2 = k0 ^ k1 ^ 0x1BD11BDAu;
  x0 += k0; x1 += k1;
  threefry_rounds(k0, k1, ks2, x0, x1);
}

// ---------------- top-4 helpers (key = (mant23 << 32) | ~index) ----------------
__device__ __forceinline__ void top4_insert(unsigned long long a[4], unsigned long long key){
  if (key > a[3]){
    if (key > a[0]){ a[3]=a[2]; a[2]=a[1]; a[1]=a[0]; a[0]=key; }
    else if (key > a[1]){ a[3]=a[2]; a[2]=a[1]; a[1]=key; }
    else if (key > a[2]){ a[3]=a[2]; a[2]=key; }
    else { a[3]=key; }
  }
}

__device__ __forceinline__ unsigned long long u64max(unsigned long long x, unsigned long long y){
  return (x >= y) ? x : y;
}
__device__ __forceinline__ unsigned long long u64min(unsigned long long x, unsigned long long y){
  return (x >= y) ? y : x;
}

// xor-butterfly merge of per-lane sorted-desc top4 lists across a 64-lane wave.
// After the loop every lane holds the wave-wide top4 (sorted desc). Static indexing only.
__device__ __forceinline__ void wave_merge_top4(unsigned long long a[4]){
  #pragma unroll
  for (int d = 1; d < 64; d <<= 1){
    unsigned long long b0 = __shfl_xor(a[0], d, 64);
    unsigned long long b1 = __shfl_xor(a[1], d, 64);
    unsigned long long b2 = __shfl_xor(a[2], d, 64);
    unsigned long long b3 = __shfl_xor(a[3], d, 64);
    // bitonic split: top-4 of the union, bitonic order
    unsigned long long L0 = u64max(a[0], b3);
    unsigned long long L1 = u64max(a[1], b2);
    unsigned long long L2 = u64max(a[2], b1);
    unsigned long long L3 = u64max(a[3], b0);
    // bitonic merge (4 elems, desc)
    unsigned long long m0 = u64max(L0, L2), m2 = u64min(L0, L2);
    unsigned long long m1 = u64max(L1, L3), m3 = u64min(L1, L3);
    a[0] = u64max(m0, m1); a[1] = u64min(m0, m1);
    a[2] = u64max(m2, m3); a[3] = u64min(m2, m3);
  }
}

__device__ __forceinline__ unsigned int lane_lt_count(unsigned long long m){
  unsigned int c = __builtin_amdgcn_mbcnt_lo((uint32_t)m, 0u);
  return __builtin_amdgcn_mbcnt_hi((uint32_t)(m >> 32), c);
}

// ---------------- sampling ----------------
#if JAX_PARTITIONABLE
// split (foldlike): key_t = (y0,y1) of threefry((0,42), 0, t)
// bits[j] = y0^y1 of threefry(key_t, 0, j), j = b*N_PTS + i ; uniform mant = bits>>9
// Threshold filter: P(bits >= TH_BITS) = 0.0064/pt => ~64 survivors/row (~16/wave).
// Ballot + mbcnt compaction into per-wave LDS regions; wave 0 takes exact top-4
// of survivors via in-register butterfly merge. Exact-rescan fallback guards
// count<4 / per-wave cap overflow => unconditionally exact.
#define TH_BITS 4267479552u   // (8388608 - 53687) << 9
#define WCAP 96               // per-wave candidate cap; survivors/wave ~ Poisson(16)

__global__ __launch_bounds__(256) void sample_topk(int* __restrict__ idxs){
  const int b = blockIdx.x;      // row 0..2047
  const int t = blockIdx.y;      // iteration 0..9
  const int tid = threadIdx.x;
  uint32_t k0 = 0u, k1 = (uint32_t)t;
  threefry2x32(0u, 42u, k0, k1);           // iteration key (both halves)
  const uint32_t ks2 = k0 ^ k1 ^ 0x1BD11BDAu;

  __shared__ unsigned long long wcand[4*WCAP];
  __shared__ unsigned int wcnts[4];

  const unsigned int wbase = (unsigned int)(tid >> 6) * WCAP;
  unsigned int wcnt = 0;                   // wave-uniform survivor count (SGPR)

  const uint32_t jb = (uint32_t)(b * N_PTS) + k1;   // x1 init = j + k1 (wrapping, as JAX)

#define EMIT(u, idx) { \
    unsigned long long mk = __ballot((u) >= TH_BITS); \
    if (mk){ \
      if ((u) >= TH_BITS){ \
        unsigned int slot = wcnt + lane_lt_count(mk); \
        if (slot < WCAP) \
          wcand[wbase + slot] = ((unsigned long long)((u) >> 9) << 32) | (uint32_t)(~(idx)); \
      } \
      wcnt += (unsigned int)__popcll(mk); \
    } }

  // 10 iterations x 4 chains x 256 threads = 10240 >= N_PTS; OOB masked on last iter
  uint32_t x1b = jb + (uint32_t)tid;
  for (int iter = 0; iter < 10; ++iter, x1b += 1024u){
    uint32_t a0=k0, a1=k0, a2=k0, a3=k0;
    uint32_t b0=x1b, b1=x1b+256u, b2=x1b+512u, b3=x1b+768u;
#define QR4(r) { a0+=b0; b0=ROTL(b0,r); b0^=a0;  a1+=b1; b1=ROTL(b1,r); b1^=a1; \
                 a2+=b2; b2=ROTL(b2,r); b2^=a2;  a3+=b3; b3=ROTL(b3,r); b3^=a3; }
#define INJ4(p,q) { a0+=(p); b0+=(q); a1+=(p); b1+=(q); a2+=(p); b2+=(q); a3+=(p); b3+=(q); }
    QR4(13) QR4(15) QR4(26) QR4(6)
    INJ4(k1,  ks2 + 1u)
    QR4(17) QR4(29) QR4(16) QR4(24)
    INJ4(ks2, k0 + 2u)
    QR4(13) QR4(15) QR4(26) QR4(6)
    INJ4(k0,  k1 + 3u)
    QR4(17) QR4(29) QR4(16) QR4(24)
    INJ4(k1,  ks2 + 4u)
    QR4(13) QR4(15) QR4(26) QR4(6)
    INJ4(ks2, k0 + 5u)
#undef QR4
#undef INJ4
    uint32_t u0 = a0^b0, u1 = a1^b1, u2 = a2^b2, u3 = a3^b3;
    const uint32_t ibase = (uint32_t)(iter*1024) + (uint32_t)tid;
    if (iter == 9){                        // mask points >= N_PTS (uniform branch)
      u0 = (ibase        < (uint32_t)N_PTS) ? u0 : 0u;
      u1 = (ibase + 256u < (uint32_t)N_PTS) ? u1 : 0u;
      u2 = (ibase + 512u < (uint32_t)N_PTS) ? u2 : 0u;
      u3 = (ibase + 768u < (uint32_t)N_PTS) ? u3 : 0u;
    }
    EMIT(u0, ibase)
    EMIT(u1, ibase + 256u)
    EMIT(u2, ibase + 512u)
    EMIT(u3, ibase + 768u)
  }
#undef EMIT

  if ((tid & 63) == 0) wcnts[tid >> 6] = wcnt;
  __syncthreads();
  const unsigned int c0 = wcnts[0], c1 = wcnts[1], c2 = wcnts[2], c3 = wcnts[3];
  const unsigned int n = c0 + c1 + c2 + c3;
  const bool good = (n >= 4u) && (c0 <= WCAP) && (c1 <= WCAP) && (c2 <= WCAP) && (c3 <= WCAP);

  if (!good){
    // exact fallback (probability ~1e-20 per row; correctness guarantee):
    // each wave scans all points strided, merges within-wave, publishes its top4.
    unsigned long long a[4] = {0ull,0ull,0ull,0ull};
    for (int i = tid; i < N_PTS; i += 256){
      uint32_t x0 = k0, x1 = jb + (uint32_t)i;
      threefry_rounds(k0, k1, ks2, x0, x1);
      uint32_t u = x0 ^ x1;
      unsigned long long key = ((unsigned long long)(u >> 9) << 32) | (uint32_t)(~(uint32_t)i);
      top4_insert(a, key);
    }
    wave_merge_top4(a);
    if ((tid & 63) == 0){
      const unsigned int w = tid >> 6;
      wcand[w*WCAP+0]=a[0]; wcand[w*WCAP+1]=a[1]; wcand[w*WCAP+2]=a[2]; wcand[w*WCAP+3]=a[3];
      wcnts[w] = 4u;
    }
    __syncthreads();
  }

  if (tid < 64){
    unsigned long long a[4] = {0ull,0ull,0ull,0ull};
    #pragma unroll
    for (int w = 0; w < 4; ++w){
      unsigned int cw = wcnts[w]; if (cw > WCAP) cw = WCAP;
      for (unsigned int j = (unsigned int)tid; j < cw; j += 64u)
        top4_insert(a, wcand[w*WCAP + j]);
    }
    wave_merge_top4(a);
    if (tid == 0){
      int base = ((t*BATCH)+b)*4;
      idxs[base+0] = (int)(~(uint32_t)(a[0] & 0xffffffffull));
      idxs[base+1] = (int)(~(uint32_t)(a[1] & 0xffffffffull));
      idxs[base+2] = (int)(~(uint32_t)(a[2] & 0xffffffffull));
      idxs[base+3] = (int)(~(uint32_t)(a[3] & 0xffffffffull));
    }
  }
}
#else
__global__ __launch_bounds__(256) void sample_topk(int* __restrict__ idxs){
  const int b = blockIdx.x;
  const int t = blockIdx.y;
  const int tid = threadIdx.x;
  uint32_t k0, k1;
  {
    int i0 = 2*t, i1 = 2*t+1;
    uint32_t u0, u1;
    if (i0 < 10){ u0=(uint32_t)i0; u1=(uint32_t)(i0+10); threefry2x32(0u,42u,u0,u1); k0=u0; }
    else        { u0=(uint32_t)(i0-10); u1=(uint32_t)i0; threefry2x32(0u,42u,u0,u1); k0=u1; }
    if (i1 < 10){ u0=(uint32_t)i1; u1=(uint32_t)(i1+10); threefry2x32(0u,42u,u0,u1); k1=u0; }
    else        { u0=(uint32_t)(i1-10); u1=(uint32_t)i1; threefry2x32(0u,42u,u0,u1); k1=u1; }
  }
  const uint32_t half = 10240000u;
  unsigned long long aLo[4] = {0,0,0,0}, aHi[4] = {0,0,0,0};
  const uint32_t jbase = (uint32_t)(b * N_PTS);
  for (int i = tid; i < N_PTS; i += 256){
    uint32_t x0 = jbase + (uint32_t)i, x1 = x0 + half;
    threefry2x32(k0, k1, x0, x1);
    unsigned long long kLo = ((unsigned long long)(x0 >> 9) << 32) | (uint32_t)(~(uint32_t)i);
    unsigned long long kHi = ((unsigned long long)(x1 >> 9) << 32) | (uint32_t)(~(uint32_t)i);
    top4_insert(aLo, kLo);
    top4_insert(aHi, kHi);
  }
  __shared__ unsigned long long wc[4*4];
  __shared__ unsigned int dummy;
  (void)dummy;
  wave_merge_top4(aLo);
  if ((tid&63)==0){ int w=tid>>6; wc[w*4+0]=aLo[0];wc[w*4+1]=aLo[1];wc[w*4+2]=aLo[2];wc[w*4+3]=aLo[3]; }
  __syncthreads();
  if (tid < 64){
    unsigned long long a[4]={0,0,0,0};
    for (int w=0;w<4;w++) if ((unsigned)tid < 4u) {}
    for (int w=0;w<4;w++) for (unsigned int j=tid;j<4u;j+=64u) top4_insert(a, wc[w*4+j]);
    wave_merge_top4(a);
    if (tid==0){ int base=((t*BATCH)+b)*4; for (int s=0;s<4;s++) idxs[base+s]=(int)(~(uint32_t)(a[s]&0xffffffffull)); }
  }
  __syncthreads();
  wave_merge_top4(aHi);
  if ((tid&63)==0){ int w=tid>>6; wc[w*4+0]=aHi[0];wc[w*4+1]=aHi[1];wc[w*4+2]=aHi[2];wc[w*4+3]=aHi[3]; }
  __syncthreads();
  if (tid < 64){
    unsigned long long a[4]={0,0,0,0};
    for (int w=0;w<4;w++) for (unsigned int j=tid;j<4u;j+=64u) top4_insert(a, wc[w*4+j]);
    wave_merge_top4(a);
    if (tid==0){ int base=((t*BATCH)+(b+1024))*4; for (int s=0;s<4;s++) idxs[base+s]=(int)(~(uint32_t)(a[s]&0xffffffffull)); }
  }
}
#endif

// ---------------- DLT: 4-point normalized homography, double precision ----------------
__global__ __launch_bounds__(64) void dlt_kernel(const float* __restrict__ kp1,
                                                 const float* __restrict__ kp2,
                                                 const int* __restrict__ idxs,
                                                 float* __restrict__ Hout,
                                                 float* __restrict__ Hinvout,
                                                 int* __restrict__ validout){
  const int m = blockIdx.x*64 + threadIdx.x;   // grid exact: 320*64 == NMODELS
  __shared__ double As[64][73];
  double* A = &As[threadIdx.x][0];

  double p1x[4],p1y[4],p2x[4],p2y[4];
  #pragma unroll
  for (int s=0;s<4;s++){
    int id = idxs[m*4+s];
    float2 a = ((const float2*)kp1)[id];
    float2 b = ((const float2*)kp2)[id];
    p1x[s]=a.x; p1y[s]=a.y; p2x[s]=b.x; p2y[s]=b.y;
  }
  double mx1=0,my1=0,mx2=0,my2=0;
  #pragma unroll
  for (int s=0;s<4;s++){ mx1+=p1x[s]; my1+=p1y[s]; mx2+=p2x[s]; my2+=p2y[s]; }
  mx1*=0.25; my1*=0.25; mx2*=0.25; my2*=0.25;
  double d1=0,d2=0;
  #pragma unroll
  for (int s=0;s<4;s++){
    d1 += sqrt((p1x[s]-mx1)*(p1x[s]-mx1) + (p1y[s]-my1)*(p1y[s]-my1));
    d2 += sqrt((p2x[s]-mx2)*(p2x[s]-mx2) + (p2y[s]-my2)*(p2y[s]-my2));
  }
  d1*=0.25; d2*=0.25;
  const double s1 = sqrt(2.0)/(d1 + 1e-8);
  const double s2 = sqrt(2.0)/(d2 + 1e-8);
  #pragma unroll
  for (int s=0;s<4;s++){
    double X1=(p1x[s]-mx1)*s1, Y1=(p1y[s]-my1)*s1;
    double X2=(p2x[s]-mx2)*s2, Y2=(p2y[s]-my2)*s2;
    double* ra = A + s*9;
    ra[0]=0.0; ra[1]=0.0; ra[2]=0.0; ra[3]=-X1; ra[4]=-Y1; ra[5]=-1.0;
    ra[6]=Y2*X1; ra[7]=Y2*Y1; ra[8]=Y2;
    double* rb = A + (4+s)*9;
    rb[0]=X1; rb[1]=Y1; rb[2]=1.0; rb[3]=0.0; rb[4]=0.0; rb[5]=0.0;
    rb[6]=-X2*X1; rb[7]=-X2*Y1; rb[8]=-X2;
  }
  for (int k=0;k<8;k++){
    int piv=k; double pv=fabs(A[k*9+k]);
    for (int r=k+1;r<8;r++){ double v=fabs(A[r*9+k]); if (v>pv){pv=v;piv=r;} }
    if (piv!=k){
      for (int c=k;c<9;c++){ double tmp=A[k*9+c]; A[k*9+c]=A[piv*9+c]; A[piv*9+c]=tmp; }
    }
    double invp = 1.0/A[k*9+k];
    for (int r=k+1;r<8;r++){
      double f = A[r*9+k]*invp;
      for (int c=k+1;c<9;c++) A[r*9+c] -= f*A[k*9+c];
      A[r*9+k]=0.0;
    }
  }
  double h[9];
  h[8]=1.0;
  for (int k=7;k>=0;k--){
    double ssum=0.0;
    for (int c=k+1;c<9;c++) ssum += A[k*9+c]*h[c];
    h[k] = -ssum / A[k*9+k];
  }
  {
    double nn=0.0;
    #pragma unroll
    for (int i=0;i<9;i++) nn += h[i]*h[i];
    double inr = 1.0/sqrt(nn);
    #pragma unroll
    for (int i=0;i<9;i++) h[i]*=inr;
  }
  double M[9];
  #pragma unroll
  for (int r=0;r<3;r++){
    double h0=h[r*3+0], h1=h[r*3+1], h2=h[r*3+2];
    M[r*3+0] = h0*s1;
    M[r*3+1] = h1*s1;
    M[r*3+2] = h0*(-s1*mx1) + h1*(-s1*my1) + h2;
  }
  double Hd[9];
  const double is2 = 1.0/s2;
  #pragma unroll
  for (int c=0;c<3;c++){
    Hd[0*3+c] = M[0*3+c]*is2 + mx2*M[2*3+c];
    Hd[1*3+c] = M[1*3+c]*is2 + my2*M[2*3+c];
    Hd[2*3+c] = M[2*3+c];
  }
  const double dn = 1.0/(Hd[8] + 1e-8);
  #pragma unroll
  for (int i=0;i<9;i++) Hd[i]*=dn;
  float Hf[9];
  #pragma unroll
  for (int i=0;i<9;i++){ Hf[i]=(float)Hd[i]; Hout[m*9+i]=Hf[i]; }
  float mind = fminf(fminf(fabsf(Hf[0]),fabsf(Hf[4])),fabsf(Hf[8]));
  validout[m] = (mind > 1e-6f) ? 1 : 0;
  {
    double a=Hd[0],b=Hd[1],c=Hd[2],d=Hd[3],e=Hd[4],f=Hd[5],g=Hd[6],hh=Hd[7],ii=Hd[8];
    double C00= e*ii-f*hh, C01=-(d*ii-f*g), C02= d*hh-e*g;
    double det = a*C00 + b*C01 + c*C02;
    double idet = 1.0/det;
    double inv[9];
    inv[0]=C00*idet;        inv[1]=(c*hh-b*ii)*idet; inv[2]=(b*f-c*e)*idet;
    inv[3]=C01*idet;        inv[4]=(a*ii-c*g)*idet;  inv[5]=(c*d-a*f)*idet;
    inv[6]=C02*idet;        inv[7]=(b*g-a*hh)*idet;  inv[8]=(a*e-b*d)*idet;
    #pragma unroll
    for (int i=0;i<9;i++) Hinvout[m*9+i]=(float)inv[i];
  }
}

// ---------------- symmetric transfer error, f32, contraction-free ----------------
// e2 >= 0 (or NaN->false), so e1 > 2.0 already decides "not inlier" — bit-exact early exit.
__device__ __forceinline__ int inlier_test(float x1,float y1,float x2,float y2,
                                           const float* __restrict__ H,
                                           const float* __restrict__ Hi){
  float px = __fadd_rn(__fadd_rn(__fmul_rn(H[0],x1), __fmul_rn(H[1],y1)), H[2]);
  float py = __fadd_rn(__fadd_rn(__fmul_rn(H[3],x1), __fmul_rn(H[4],y1)), H[5]);
  float pz = __fadd_rn(__fadd_rn(__fmul_rn(H[6],x1), __fmul_rn(H[7],y1)), H[8]);
  float sc = (fabsf(pz) > 1e-8f) ? __fdiv_rn(1.0f, pz) : 1.0f;
  float dx = __fsub_rn(__fmul_rn(px,sc), x2);
  float dy = __fsub_rn(__fmul_rn(py,sc), y2);
  float e1 = __fadd_rn(__fmul_rn(dx,dx), __fmul_rn(dy,dy));
  if (!(e1 <= 2.0f)) return 0;          // covers e1 > 2 and e1 = NaN
  float qx = __fadd_rn(__fadd_rn(__fmul_rn(Hi[0],x2), __fmul_rn(Hi[1],y2)), Hi[2]);
  float qy = __fadd_rn(__fadd_rn(__fmul_rn(Hi[3],x2), __fmul_rn(Hi[4],y2)), Hi[5]);
  float qz = __fadd_rn(__fadd_rn(__fmul_rn(Hi[6],x2), __fmul_rn(Hi[7],y2)), Hi[8]);
  float sc2 = (fabsf(qz) > 1e-8f) ? __fdiv_rn(1.0f, qz) : 1.0f;
  float ex = __fsub_rn(__fmul_rn(qx,sc2), x1);
  float ey = __fsub_rn(__fmul_rn(qy,sc2), y1);
  float e2 = __fadd_rn(__fmul_rn(ex,ex), __fmul_rn(ey,ey));
  float err = __fadd_rn(e1, e2);
  return (err <= 2.0f) ? 1 : 0;   // NaN -> 0, matches jnp
}

// ---------------- scoring: 4 models per block (round-3 measured-good config) ----------------
#define MODELS_PER_BLOCK 4
__global__ __launch_bounds__(256) void score_kernel(const float* __restrict__ kp1,
                                                    const float* __restrict__ kp2,
                                                    const float* __restrict__ Hall,
                                                    const float* __restrict__ Hinvall,
                                                    const int* __restrict__ validall,
                                                    float* __restrict__ scores){
  const int m0 = blockIdx.x * MODELS_PER_BLOCK;
  const int tid = threadIdx.x;
  __shared__ float sH[MODELS_PER_BLOCK][9], sHi[MODELS_PER_BLOCK][9];
  if (tid < 9*MODELS_PER_BLOCK)        sH [tid/9][tid%9] = Hall[m0*9 + tid];
  else if (tid < 18*MODELS_PER_BLOCK){ int q = tid - 9*MODELS_PER_BLOCK;
                                       sHi[q/9][q%9] = Hinvall[m0*9 + q]; }
  __syncthreads();
  int cnt[MODELS_PER_BLOCK];
  #pragma unroll
  for (int mm=0;mm<MODELS_PER_BLOCK;mm++) cnt[mm]=0;
  for (int i = tid; i < N_PTS; i += 256){
    float2 p1 = ((const float2*)kp1)[i];
    float2 p2 = ((const float2*)kp2)[i];
    #pragma unroll
    for (int mm=0;mm<MODELS_PER_BLOCK;mm++)
      cnt[mm] += inlier_test(p1.x,p1.y,p2.x,p2.y,sH[mm],sHi[mm]);
  }
  __shared__ int red[256];
  #pragma unroll
  for (int mm=0;mm<MODELS_PER_BLOCK;mm++){
    red[tid]=cnt[mm]; __syncthreads();
    for (int s=128;s;s>>=1){ if (tid<s) red[tid]+=red[tid+s]; __syncthreads(); }
    if (tid==0) scores[m0+mm] = validall[m0+mm] ? (float)red[0] : -1.0f;
    __syncthreads();
  }
}

// ---------------- selection: max score, ties -> earliest linear index ----------------
__global__ __launch_bounds__(1024) void select_kernel(const float* __restrict__ scores,
                                                      int* __restrict__ winner){
  __shared__ unsigned long long sm[1024];
  const int tid = threadIdx.x;
  unsigned long long best = 0ull;
  for (int i = tid; i < NMODELS; i += 1024){
    float s = scores[i];
    uint32_t hi = (uint32_t)(int)(s + 2.0f);   // -1 -> 1, count c -> c+2 (exact ints)
    unsigned long long key = ((unsigned long long)hi << 32) | (uint32_t)(~(uint32_t)i);
    if (key > best) best = key;
  }
  sm[tid]=best; __syncthreads();
  for (int s=512;s;s>>=1){ if (tid<s && sm[tid+s]>sm[tid]) sm[tid]=sm[tid+s]; __syncthreads(); }
  if (tid==0){
    unsigned long long k = sm[0];
    winner[0] = (int)(~(uint32_t)(k & 0xffffffffull));
    winner[1] = ((uint32_t)(k >> 32) >= 4u) ? 1 : 0;  // score>=2 beats init best_score=1.0
  }
}

// ---------------- finalize: write H + inlier mask ----------------
__global__ __launch_bounds__(256) void finalize_kernel(const float* __restrict__ kp1,
                                                       const float* __restrict__ kp2,
                                                       const float* __restrict__ Hall,
                                                       const float* __restrict__ Hinvall,
                                                       const int* __restrict__ winner,
                                                       float* __restrict__ out){
  __shared__ float sH[9], sHi[9];
  const int w = winner[0];
  const int ok = winner[1];
  if (threadIdx.x < 9){
    float idv = (threadIdx.x % 4 == 0) ? 1.0f : 0.0f;
    sH[threadIdx.x]  = ok ? Hall[w*9+threadIdx.x]    : idv;
    sHi[threadIdx.x] = ok ? Hinvall[w*9+threadIdx.x] : idv;
  }
  __syncthreads();
  if (blockIdx.x==0 && threadIdx.x<9) out[threadIdx.x] = sH[threadIdx.x];
  const int i = blockIdx.x*256 + threadIdx.x;
  if (i < N_PTS){
    float2 p1 = ((const float2*)kp1)[i];
    float2 p2 = ((const float2*)kp2)[i];
    int inl = ok ? inlier_test(p1.x,p1.y,p2.x,p2.y,sH,sHi) : 0;
    out[9+i] = inl ? 1.0f : 0.0f;
  }
}

// ---------------- launch ----------------
extern "C" void kernel_launch(void* const* d_in, const int* in_sizes, int n_in,
                              void* d_out, int out_size, void* d_ws, size_t ws_size,
                              hipStream_t stream) {
  (void)in_sizes; (void)n_in; (void)out_size; (void)ws_size;
  const float* kp1 = (const float*)d_in[0];
  const float* kp2 = (const float*)d_in[1];
  float* out = (float*)d_out;
  char* ws = (char*)d_ws;
  int*   idxs    = (int*)  (ws + 0);          // NMODELS*4 int  = 327,680 B
  float* Hall    = (float*)(ws + 327680);     // NMODELS*9 f32  = 737,280 B
  float* Hinvall = (float*)(ws + 1064960);    // NMODELS*9 f32  = 737,280 B
  int*   validall= (int*)  (ws + 1802240);    // NMODELS int    =  81,920 B
  float* scores  = (float*)(ws + 1884160);    // NMODELS f32    =  81,920 B
  int*   winner  = (int*)  (ws + 1966080);    // 2 ints

#if JAX_PARTITIONABLE
  sample_topk<<<dim3(BATCH, MAX_ITER), 256, 0, stream>>>(idxs);
#else
  sample_topk<<<dim3(BATCH/2, MAX_ITER), 256, 0, stream>>>(idxs);
#endif
  dlt_kernel<<<dim3(NMODELS/64), 64, 0, stream>>>(kp1, kp2, idxs, Hall, Hinvall, validall);
  score_kernel<<<dim3(NMODELS/MODELS_PER_BLOCK), 256, 0, stream>>>(kp1, kp2, Hall, Hinvall, validall, scores);
  select_kernel<<<1, 1024, 0, stream>>>(scores, winner);
  finalize_kernel<<<dim3((N_PTS+255)/256), 256, 0, stream>>>(kp1, kp2, Hall, Hinvall, winner, out);
}

// Round 7
// 725.932 us; speedup vs baseline: 1.0807x; 1.0023x over previous
//
#include <hip/hip_runtime.h>
#include <stdint.h>

#define JAX_PARTITIONABLE 1

#define N_PTS    10000
#define BATCH    2048
#define MAX_ITER 10
#define NMODELS  (BATCH*MAX_ITER)

// ---------------- threefry2x32 (JAX-exact, 20 rounds) ----------------
#define ROTL(v,d) __builtin_amdgcn_alignbit((v),(v),(uint32_t)(32-(d)))

__device__ __forceinline__ void threefry_rounds(uint32_t k0, uint32_t k1, uint32_t ks2,
                                                uint32_t &x0, uint32_t &x1){
#define TF_R(r) { x0 += x1; x1 = ROTL(x1,(r)); x1 ^= x0; }
  TF_R(13) TF_R(15) TF_R(26) TF_R(6)
  x0 += k1;  x1 += ks2 + 1u;
  TF_R(17) TF_R(29) TF_R(16) TF_R(24)
  x0 += ks2; x1 += k0 + 2u;
  TF_R(13) TF_R(15) TF_R(26) TF_R(6)
  x0 += k0;  x1 += k1 + 3u;
  TF_R(17) TF_R(29) TF_R(16) TF_R(24)
  x0 += k1;  x1 += ks2 + 4u;
  TF_R(13) TF_R(15) TF_R(26) TF_R(6)
  x0 += ks2; x1 += k0 + 5u;
#undef TF_R
}

__device__ __forceinline__ void threefry2x32(uint32_t k0, uint32_t k1, uint32_t &x0, uint32_t &x1){
  const uint32_t ks2 = k0 ^ k1 ^ 0x1BD11BDAu;
  x0 += k0; x1 += k1;
  threefry_rounds(k0, k1, ks2, x0, x1);
}

// ---------------- top-4 helpers (key = (mant23 << 32) | ~index) ----------------
__device__ __forceinline__ void top4_insert(unsigned long long a[4], unsigned long long key){
  if (key > a[3]){
    if (key > a[0]){ a[3]=a[2]; a[2]=a[1]; a[1]=a[0]; a[0]=key; }
    else if (key > a[1]){ a[3]=a[2]; a[2]=a[1]; a[1]=key; }
    else if (key > a[2]){ a[3]=a[2]; a[2]=key; }
    else { a[3]=key; }
  }
}

__device__ __forceinline__ unsigned long long u64max(unsigned long long x, unsigned long long y){
  return (x >= y) ? x : y;
}
__device__ __forceinline__ unsigned long long u64min(unsigned long long x, unsigned long long y){
  return (x >= y) ? y : x;
}

// xor-butterfly merge of per-lane sorted-desc top4 lists across a 64-lane wave.
__device__ __forceinline__ void wave_merge_top4(unsigned long long a[4]){
  #pragma unroll
  for (int d = 1; d < 64; d <<= 1){
    unsigned long long b0 = __shfl_xor(a[0], d, 64);
    unsigned long long b1 = __shfl_xor(a[1], d, 64);
    unsigned long long b2 = __shfl_xor(a[2], d, 64);
    unsigned long long b3 = __shfl_xor(a[3], d, 64);
    unsigned long long L0 = u64max(a[0], b3);
    unsigned long long L1 = u64max(a[1], b2);
    unsigned long long L2 = u64max(a[2], b1);
    unsigned long long L3 = u64max(a[3], b0);
    unsigned long long m0 = u64max(L0, L2), m2 = u64min(L0, L2);
    unsigned long long m1 = u64max(L1, L3), m3 = u64min(L1, L3);
    a[0] = u64max(m0, m1); a[1] = u64min(m0, m1);
    a[2] = u64max(m2, m3); a[3] = u64min(m2, m3);
  }
}

__device__ __forceinline__ unsigned int lane_lt_count(unsigned long long m){
  unsigned int c = __builtin_amdgcn_mbcnt_lo((uint32_t)m, 0u);
  return __builtin_amdgcn_mbcnt_hi((uint32_t)(m >> 32), c);
}

// ---------------- sampling (round-5 structure, measured floor ~557us) ----------------
#define TH_BITS 4267479552u   // (8388608 - 53687) << 9 ; p = 0.0064/pt => ~64 survivors/row
#define WCAP 96

__global__ __launch_bounds__(256) void sample_topk(int* __restrict__ idxs){
  const int b = blockIdx.x;      // row 0..2047
  const int t = blockIdx.y;      // iteration 0..9
  const int tid = threadIdx.x;
  uint32_t k0 = 0u, k1 = (uint32_t)t;
  threefry2x32(0u, 42u, k0, k1);           // iteration key (both halves)
  const uint32_t ks2 = k0 ^ k1 ^ 0x1BD11BDAu;

  __shared__ unsigned long long wcand[4*WCAP];
  __shared__ unsigned int wcnts[4];

  const unsigned int wbase = (unsigned int)(tid >> 6) * WCAP;
  unsigned int wcnt = 0;

  const uint32_t jb = (uint32_t)(b * N_PTS) + k1;

#define EMIT(u, idx) { \
    unsigned long long mk = __ballot((u) >= TH_BITS); \
    if (mk){ \
      if ((u) >= TH_BITS){ \
        unsigned int slot = wcnt + lane_lt_count(mk); \
        if (slot < WCAP) \
          wcand[wbase + slot] = ((unsigned long long)((u) >> 9) << 32) | (uint32_t)(~(idx)); \
      } \
      wcnt += (unsigned int)__popcll(mk); \
    } }

  uint32_t x1b = jb + (uint32_t)tid;
  for (int iter = 0; iter < 10; ++iter, x1b += 1024u){
    uint32_t a0=k0, a1=k0, a2=k0, a3=k0;
    uint32_t b0=x1b, b1=x1b+256u, b2=x1b+512u, b3=x1b+768u;
#define QR4(r) { a0+=b0; b0=ROTL(b0,r); b0^=a0;  a1+=b1; b1=ROTL(b1,r); b1^=a1; \
                 a2+=b2; b2=ROTL(b2,r); b2^=a2;  a3+=b3; b3=ROTL(b3,r); b3^=a3; }
#define INJ4(p,q) { a0+=(p); b0+=(q); a1+=(p); b1+=(q); a2+=(p); b2+=(q); a3+=(p); b3+=(q); }
    QR4(13) QR4(15) QR4(26) QR4(6)
    INJ4(k1,  ks2 + 1u)
    QR4(17) QR4(29) QR4(16) QR4(24)
    INJ4(ks2, k0 + 2u)
    QR4(13) QR4(15) QR4(26) QR4(6)
    INJ4(k0,  k1 + 3u)
    QR4(17) QR4(29) QR4(16) QR4(24)
    INJ4(k1,  ks2 + 4u)
    QR4(13) QR4(15) QR4(26) QR4(6)
    INJ4(ks2, k0 + 5u)
#undef QR4
#undef INJ4
    uint32_t u0 = a0^b0, u1 = a1^b1, u2 = a2^b2, u3 = a3^b3;
    const uint32_t ibase = (uint32_t)(iter*1024) + (uint32_t)tid;
    if (iter == 9){
      u0 = (ibase        < (uint32_t)N_PTS) ? u0 : 0u;
      u1 = (ibase + 256u < (uint32_t)N_PTS) ? u1 : 0u;
      u2 = (ibase + 512u < (uint32_t)N_PTS) ? u2 : 0u;
      u3 = (ibase + 768u < (uint32_t)N_PTS) ? u3 : 0u;
    }
    EMIT(u0, ibase)
    EMIT(u1, ibase + 256u)
    EMIT(u2, ibase + 512u)
    EMIT(u3, ibase + 768u)
  }
#undef EMIT

  if ((tid & 63) == 0) wcnts[tid >> 6] = wcnt;
  __syncthreads();
  const unsigned int c0 = wcnts[0], c1 = wcnts[1], c2 = wcnts[2], c3 = wcnts[3];
  const unsigned int n = c0 + c1 + c2 + c3;
  const bool good = (n >= 4u) && (c0 <= WCAP) && (c1 <= WCAP) && (c2 <= WCAP) && (c3 <= WCAP);

  if (!good){
    // exact fallback (probability ~1e-20 per row)
    unsigned long long a[4] = {0ull,0ull,0ull,0ull};
    for (int i = tid; i < N_PTS; i += 256){
      uint32_t x0 = k0, x1 = jb + (uint32_t)i;
      threefry_rounds(k0, k1, ks2, x0, x1);
      uint32_t u = x0 ^ x1;
      unsigned long long key = ((unsigned long long)(u >> 9) << 32) | (uint32_t)(~(uint32_t)i);
      top4_insert(a, key);
    }
    wave_merge_top4(a);
    if ((tid & 63) == 0){
      const unsigned int w = tid >> 6;
      wcand[w*WCAP+0]=a[0]; wcand[w*WCAP+1]=a[1]; wcand[w*WCAP+2]=a[2]; wcand[w*WCAP+3]=a[3];
      wcnts[w] = 4u;
    }
    __syncthreads();
  }

  if (tid < 64){
    unsigned long long a[4] = {0ull,0ull,0ull,0ull};
    #pragma unroll
    for (int w = 0; w < 4; ++w){
      unsigned int cw = wcnts[w]; if (cw > WCAP) cw = WCAP;
      for (unsigned int j = (unsigned int)tid; j < cw; j += 64u)
        top4_insert(a, wcand[w*WCAP + j]);
    }
    wave_merge_top4(a);
    if (tid == 0){
      int base = ((t*BATCH)+b)*4;
      idxs[base+0] = (int)(~(uint32_t)(a[0] & 0xffffffffull));
      idxs[base+1] = (int)(~(uint32_t)(a[1] & 0xffffffffull));
      idxs[base+2] = (int)(~(uint32_t)(a[2] & 0xffffffffull));
      idxs[base+3] = (int)(~(uint32_t)(a[3] & 0xffffffffull));
    }
  }
}

// ---------------- DLT: register-resident pivotless GE, row order [a0,a1,a2,b0,b1,b2,a3,b3]
// a = [X1,Y1,1, 0,0,0, -X2X1,-X2Y1,-X2], b = [0,0,0, -X1,-Y1,-1, Y2X1,Y2Y1,Y2].
// Leading minors: 1-3 from a-block (generic); 4-6 = det(a3x3)*det(b kxk) (generic);
// 7-8 generic (8x8 nonsingular iff H22 != 0, which ref's H/(H22+eps) already assumes).
// Structural skips: b-rows (3,4,5,7) have cols0-2 == 0 through k<3; a3 (row 6) has
// cols3-5 == 0 through k in {3,4,5} (rows 0-2 have zeros there, so its updates at
// k<3 never touch cols 3-5). Degenerate sample -> inf/NaN -> valid=0 (as before).
__global__ __launch_bounds__(64, 1) void dlt_kernel(const float* __restrict__ kp1,
                                                    const float* __restrict__ kp2,
                                                    const int* __restrict__ idxs,
                                                    float* __restrict__ Hout,
                                                    float* __restrict__ Hinvout,
                                                    int* __restrict__ validout){
  const int m = blockIdx.x*64 + threadIdx.x;   // grid exact: 320*64 == NMODELS

  double p1x[4],p1y[4],p2x[4],p2y[4];
  #pragma unroll
  for (int s=0;s<4;s++){
    int id = idxs[m*4+s];
    float2 a = ((const float2*)kp1)[id];
    float2 b = ((const float2*)kp2)[id];
    p1x[s]=a.x; p1y[s]=a.y; p2x[s]=b.x; p2y[s]=b.y;
  }
  double mx1=0,my1=0,mx2=0,my2=0;
  #pragma unroll
  for (int s=0;s<4;s++){ mx1+=p1x[s]; my1+=p1y[s]; mx2+=p2x[s]; my2+=p2y[s]; }
  mx1*=0.25; my1*=0.25; mx2*=0.25; my2*=0.25;
  double d1=0,d2=0;
  #pragma unroll
  for (int s=0;s<4;s++){
    d1 += sqrt((p1x[s]-mx1)*(p1x[s]-mx1) + (p1y[s]-my1)*(p1y[s]-my1));
    d2 += sqrt((p2x[s]-mx2)*(p2x[s]-mx2) + (p2y[s]-my2)*(p2y[s]-my2));
  }
  d1*=0.25; d2*=0.25;
  const double s1 = sqrt(2.0)/(d1 + 1e-8);
  const double s2 = sqrt(2.0)/(d2 + 1e-8);

  double A[8][9];
  #pragma unroll
  for (int s=0;s<4;s++){
    double X1=(p1x[s]-mx1)*s1, Y1=(p1y[s]-my1)*s1;
    double X2=(p2x[s]-mx2)*s2, Y2=(p2y[s]-my2)*s2;
    const int ra = (s<3) ? s : 6;       // a-rows at 0,1,2,6
    const int rb = (s<3) ? 3+s : 7;     // b-rows at 3,4,5,7
    A[ra][0]=X1;  A[ra][1]=Y1;  A[ra][2]=1.0;
    A[ra][3]=0.0; A[ra][4]=0.0; A[ra][5]=0.0;
    A[ra][6]=-X2*X1; A[ra][7]=-X2*Y1; A[ra][8]=-X2;
    A[rb][0]=0.0; A[rb][1]=0.0; A[rb][2]=0.0;
    A[rb][3]=-X1; A[rb][4]=-Y1; A[rb][5]=-1.0;
    A[rb][6]=Y2*X1; A[rb][7]=Y2*Y1; A[rb][8]=Y2;
  }
  // pivotless elimination with static structural skips
  #pragma unroll
  for (int k=0;k<8;k++){
    double invp = 1.0/A[k][k];
    #pragma unroll
    for (int r=k+1;r<8;r++){
      if (k < 3 && (r==3 || r==4 || r==5 || r==7)) continue; // b-rows: cols0-2 == 0
      if (k >= 3 && k < 6 && r == 6) continue;               // a3: cols3-5 == 0
      double f = A[r][k]*invp;
      #pragma unroll
      for (int c=k+1;c<9;c++) A[r][c] -= f*A[k][c];
    }
  }
  double h[9];
  h[8]=1.0;
  #pragma unroll
  for (int k=7;k>=0;k--){
    double ssum=0.0;
    #pragma unroll
    for (int c=k+1;c<9;c++) ssum += A[k][c]*h[c];
    h[k] = -ssum / A[k][k];
  }
  {
    double nn=0.0;
    #pragma unroll
    for (int i=0;i<9;i++) nn += h[i]*h[i];
    double inr = 1.0/sqrt(nn);
    #pragma unroll
    for (int i=0;i<9;i++) h[i]*=inr;
  }
  double M[9];
  #pragma unroll
  for (int r=0;r<3;r++){
    double h0=h[r*3+0], h1=h[r*3+1], h2=h[r*3+2];
    M[r*3+0] = h0*s1;
    M[r*3+1] = h1*s1;
    M[r*3+2] = h0*(-s1*mx1) + h1*(-s1*my1) + h2;
  }
  double Hd[9];
  const double is2 = 1.0/s2;
  #pragma unroll
  for (int c=0;c<3;c++){
    Hd[0*3+c] = M[0*3+c]*is2 + mx2*M[2*3+c];
    Hd[1*3+c] = M[1*3+c]*is2 + my2*M[2*3+c];
    Hd[2*3+c] = M[2*3+c];
  }
  const double dn = 1.0/(Hd[8] + 1e-8);
  #pragma unroll
  for (int i=0;i<9;i++) Hd[i]*=dn;
  float Hf[9];
  #pragma unroll
  for (int i=0;i<9;i++){ Hf[i]=(float)Hd[i]; Hout[m*9+i]=Hf[i]; }
  float mind = fminf(fminf(fabsf(Hf[0]),fabsf(Hf[4])),fabsf(Hf[8]));
  validout[m] = (mind > 1e-6f) ? 1 : 0;
  {
    double a=Hd[0],b=Hd[1],c=Hd[2],d=Hd[3],e=Hd[4],f=Hd[5],g=Hd[6],hh=Hd[7],ii=Hd[8];
    double C00= e*ii-f*hh, C01=-(d*ii-f*g), C02= d*hh-e*g;
    double det = a*C00 + b*C01 + c*C02;
    double idet = 1.0/det;
    double inv[9];
    inv[0]=C00*idet;        inv[1]=(c*hh-b*ii)*idet; inv[2]=(b*f-c*e)*idet;
    inv[3]=C01*idet;        inv[4]=(a*ii-c*g)*idet;  inv[5]=(c*d-a*f)*idet;
    inv[6]=C02*idet;        inv[7]=(b*g-a*hh)*idet;  inv[8]=(a*e-b*d)*idet;
    #pragma unroll
    for (int i=0;i<9;i++) Hinvout[m*9+i]=(float)inv[i];
  }
}

// ---------------- symmetric transfer error, f32, contraction-free ----------------
__device__ __forceinline__ int inlier_test(float x1,float y1,float x2,float y2,
                                           const float* __restrict__ H,
                                           const float* __restrict__ Hi){
  float px = __fadd_rn(__fadd_rn(__fmul_rn(H[0],x1), __fmul_rn(H[1],y1)), H[2]);
  float py = __fadd_rn(__fadd_rn(__fmul_rn(H[3],x1), __fmul_rn(H[4],y1)), H[5]);
  float pz = __fadd_rn(__fadd_rn(__fmul_rn(H[6],x1), __fmul_rn(H[7],y1)), H[8]);
  float sc = (fabsf(pz) > 1e-8f) ? __fdiv_rn(1.0f, pz) : 1.0f;
  float dx = __fsub_rn(__fmul_rn(px,sc), x2);
  float dy = __fsub_rn(__fmul_rn(py,sc), y2);
  float e1 = __fadd_rn(__fmul_rn(dx,dx), __fmul_rn(dy,dy));
  if (!(e1 <= 2.0f)) return 0;          // covers e1 > 2 and e1 = NaN
  float qx = __fadd_rn(__fadd_rn(__fmul_rn(Hi[0],x2), __fmul_rn(Hi[1],y2)), Hi[2]);
  float qy = __fadd_rn(__fadd_rn(__fmul_rn(Hi[3],x2), __fmul_rn(Hi[4],y2)), Hi[5]);
  float qz = __fadd_rn(__fadd_rn(__fmul_rn(Hi[6],x2), __fmul_rn(Hi[7],y2)), Hi[8]);
  float sc2 = (fabsf(qz) > 1e-8f) ? __fdiv_rn(1.0f, qz) : 1.0f;
  float ex = __fsub_rn(__fmul_rn(qx,sc2), x1);
  float ey = __fsub_rn(__fmul_rn(qy,sc2), y1);
  float e2 = __fadd_rn(__fmul_rn(ex,ex), __fmul_rn(ey,ey));
  float err = __fadd_rn(e1, e2);
  return (err <= 2.0f) ? 1 : 0;   // NaN -> 0, matches jnp
}

// ---------------- scoring: 4 models per block (measured-good config) ----------------
#define MODELS_PER_BLOCK 4
__global__ __launch_bounds__(256) void score_kernel(const float* __restrict__ kp1,
                                                    const float* __restrict__ kp2,
                                                    const float* __restrict__ Hall,
                                                    const float* __restrict__ Hinvall,
                                                    const int* __restrict__ validall,
                                                    float* __restrict__ scores){
  const int m0 = blockIdx.x * MODELS_PER_BLOCK;
  const int tid = threadIdx.x;
  __shared__ float sH[MODELS_PER_BLOCK][9], sHi[MODELS_PER_BLOCK][9];
  if (tid < 9*MODELS_PER_BLOCK)        sH [tid/9][tid%9] = Hall[m0*9 + tid];
  else if (tid < 18*MODELS_PER_BLOCK){ int q = tid - 9*MODELS_PER_BLOCK;
                                       sHi[q/9][q%9] = Hinvall[m0*9 + q]; }
  __syncthreads();
  int cnt[MODELS_PER_BLOCK];
  #pragma unroll
  for (int mm=0;mm<MODELS_PER_BLOCK;mm++) cnt[mm]=0;
  for (int i = tid; i < N_PTS; i += 256){
    float2 p1 = ((const float2*)kp1)[i];
    float2 p2 = ((const float2*)kp2)[i];
    #pragma unroll
    for (int mm=0;mm<MODELS_PER_BLOCK;mm++)
      cnt[mm] += inlier_test(p1.x,p1.y,p2.x,p2.y,sH[mm],sHi[mm]);
  }
  __shared__ int red[256];
  #pragma unroll
  for (int mm=0;mm<MODELS_PER_BLOCK;mm++){
    red[tid]=cnt[mm]; __syncthreads();
    for (int s=128;s;s>>=1){ if (tid<s) red[tid]+=red[tid+s]; __syncthreads(); }
    if (tid==0) scores[m0+mm] = validall[m0+mm] ? (float)red[0] : -1.0f;
    __syncthreads();
  }
}

// ---------------- merged select + finalize (single block, 1024 threads) -----------
__global__ __launch_bounds__(1024) void select_finalize_kernel(const float* __restrict__ kp1,
                                                               const float* __restrict__ kp2,
                                                               const float* __restrict__ Hall,
                                                               const float* __restrict__ Hinvall,
                                                               const float* __restrict__ scores,
                                                               float* __restrict__ out){
  __shared__ unsigned long long sm[1024];
  __shared__ float sH[9], sHi[9];
  const int tid = threadIdx.x;
  unsigned long long best = 0ull;
  for (int i = tid; i < NMODELS; i += 1024){
    float s = scores[i];
    uint32_t hi = (uint32_t)(int)(s + 2.0f);   // -1 -> 1, count c -> c+2 (exact ints)
    unsigned long long key = ((unsigned long long)hi << 32) | (uint32_t)(~(uint32_t)i);
    if (key > best) best = key;
  }
  sm[tid]=best; __syncthreads();
  for (int s=512;s;s>>=1){ if (tid<s && sm[tid+s]>sm[tid]) sm[tid]=sm[tid+s]; __syncthreads(); }
  const unsigned long long k = sm[0];
  const int w = (int)(~(uint32_t)(k & 0xffffffffull));
  const int ok = ((uint32_t)(k >> 32) >= 4u) ? 1 : 0;  // score>=2 beats init best_score=1.0
  if (tid < 9){
    float idv = (tid % 4 == 0) ? 1.0f : 0.0f;
    sH[tid]  = ok ? Hall[w*9+tid]    : idv;
    sHi[tid] = ok ? Hinvall[w*9+tid] : idv;
    out[tid] = sH[tid];
  }
  __syncthreads();
  for (int i = tid; i < N_PTS; i += 1024){
    float2 p1 = ((const float2*)kp1)[i];
    float2 p2 = ((const float2*)kp2)[i];
    int inl = ok ? inlier_test(p1.x,p1.y,p2.x,p2.y,sH,sHi) : 0;
    out[9+i] = inl ? 1.0f : 0.0f;
  }
}

// ---------------- launch ----------------
extern "C" void kernel_launch(void* const* d_in, const int* in_sizes, int n_in,
                              void* d_out, int out_size, void* d_ws, size_t ws_size,
                              hipStream_t stream) {
  (void)in_sizes; (void)n_in; (void)out_size; (void)ws_size;
  const float* kp1 = (const float*)d_in[0];
  const float* kp2 = (const float*)d_in[1];
  float* out = (float*)d_out;
  char* ws = (char*)d_ws;
  int*   idxs    = (int*)  (ws + 0);          // NMODELS*4 int  = 327,680 B
  float* Hall    = (float*)(ws + 327680);     // NMODELS*9 f32  = 737,280 B
  float* Hinvall = (float*)(ws + 1064960);    // NMODELS*9 f32  = 737,280 B
  int*   validall= (int*)  (ws + 1802240);    // NMODELS int    =  81,920 B
  float* scores  = (float*)(ws + 1884160);    // NMODELS f32    =  81,920 B

  sample_topk<<<dim3(BATCH, MAX_ITER), 256, 0, stream>>>(idxs);
  dlt_kernel<<<dim3(NMODELS/64), 64, 0, stream>>>(kp1, kp2, idxs, Hall, Hinvall, validall);
  score_kernel<<<dim3(NMODELS/MODELS_PER_BLOCK), 256, 0, stream>>>(kp1, kp2, Hall, Hinvall, validall, scores);
  select_finalize_kernel<<<1, 1024, 0, stream>>>(kp1, kp2, Hall, Hinvall, scores, out);
}